// Round 5
// baseline (195.448 us; speedup 1.0000x reference)
//
#include <hip/hip_runtime.h>
#include <hip/hip_cooperative_groups.h>
#include <math.h>

namespace cg = cooperative_groups;

// Problem constants
#define BB    16
#define DIMM  1024
#define TN    2048
#define NBINS 625

// Output layout (floats, concatenated in reference return order)
//   zero: 4 | feat_t: B*DIM*T | perplexity: 4 | ind_t: B*4*T
static constexpr size_t OUT_ZERO = 0;
static constexpr size_t OUT_FEAT = 4;
static constexpr size_t OUT_PERP = 4 + (size_t)BB * DIMM * TN;
static constexpr size_t OUT_IND  = OUT_PERP + 4;

// Workspace: counts only — 2500 floats @ 0.

// ---------------------------------------------------------------------------
// Single fused cooperative kernel. 512 blocks x 256 threads; block = (b, 64-t
// tile). Phases:
//   P0: first 10 blocks zero global counts; stage w_in; zero LDS hist.
//   P1: 4 waves accumulate 256 rows each (f64, matches np ref); LDS reduce;
//       tid<128 run the f64 FSQ chain, write ind, q->LDS, LDS-hist atomics.
//       Meanwhile wl4/bl are restaged with w_out/b_out (disjoint LDS use).
//   grid.sync  (counts zeroed everywhere, all per-block state ready)
//   P2: sparse-merge LDS hist -> global counts (<=512 serialized per bin,
//       hidden under P2 stores); out-projection: wave w covers dims d%4==w,
//       64 contiguous t per store (write-bound, coalesced 256B/wave).
//   grid.sync
//   P3: blocks 0..3 reduce global counts -> perplexity (f64, proven).
// ---------------------------------------------------------------------------
__global__ __launch_bounds__(256) void gfsq_fused(const float* __restrict__ x,
                                                  const float* __restrict__ w_in,
                                                  const float* __restrict__ b_in,
                                                  const float* __restrict__ w_out,
                                                  const float* __restrict__ b_out,
                                                  float* __restrict__ counts,
                                                  float* __restrict__ out) {
  const int bid  = blockIdx.x;      // 0..511
  const int tt   = bid & 31;        // 64-t tile
  const int b    = bid >> 5;
  const int tid  = threadIdx.x;
  const int w    = tid >> 6;
  const int lane = tid & 63;
  const int t    = tt * 64 + lane;

  __shared__ float4 wl4[1024];        // 16 KB: w_in rows, later w_out rows
  __shared__ double sacc[4][4][64];   // 8 KB
  __shared__ float4 qtile[64][2];     // 2 KB
  __shared__ float  bl[1024];         // 4 KB
  __shared__ float  hist[4 * NBINS];  // 10 KB
  __shared__ double red[256];         // 2 KB

  // P0: zero global counts (done before any atomic: atomics are post-sync)
  if (bid < 10) {
    const int i = bid * 256 + tid;
    if (i < 4 * NBINS) counts[i] = 0.0f;
  }
  if (bid == 10 && tid < 4) out[OUT_ZERO + tid] = 0.0f;

  for (int i = tid; i < 4 * NBINS; i += 256) hist[i] = 0.0f;
  for (int i = tid; i < 1024; i += 256) {
    const int g = i >> 9, d = i & 511;
    const float* wp = w_in + g * 2048 + d;
    wl4[i] = make_float4(wp[0], wp[512], wp[1024], wp[1536]);
  }
  __syncthreads();

  // P1: f64 accumulation, wave w owns rows [w*256, w*256+256)
  const float* xp = x + ((size_t)b * DIMM + (size_t)w * 256) * TN + t;
  const int rb = w * 256;
  double a0 = 0.0, a1 = 0.0, a2 = 0.0, a3 = 0.0;
  #pragma unroll 8
  for (int r = 0; r < 256; ++r) {
    double xv = (double)xp[(size_t)r * TN];
    float4 wv = wl4[rb + r];
    a0 += (double)wv.x * xv;
    a1 += (double)wv.y * xv;
    a2 += (double)wv.z * xv;
    a3 += (double)wv.w * xv;
  }
  sacc[w][0][lane] = a0;
  sacc[w][1][lane] = a1;
  sacc[w][2][lane] = a2;
  sacc[w][3][lane] = a3;
  __syncthreads();

  // FSQ chain (tid<128; g = w). wl4/bl restage runs on all threads after.
  if (tid < 128) {
    const int g = w;
    const double half_l = (5.0 - 1.0) * (1.0 + 1e-3) / 2.0;  // match np expr
    const int basis[4] = {1, 5, 25, 125};
    float q[4];
    int idx0 = 0, idx1 = 0;
    #pragma unroll
    for (int c = 0; c < 4; ++c) {
      double z = sacc[2 * g][c][lane] + sacc[2 * g + 1][c][lane]
               + (double)b_in[g * 4 + c];
      double n0 = rint(tanh(z) * half_l);          // step 0, s=1
      double r1 = z - 0.5 * n0;
      double n1 = rint(tanh(4.0 * r1) * half_l);   // step 1, s=0.25
      q[c] = (float)(0.5 * n0 + 0.125 * n1);       // exact in f32
      idx0 += ((int)n0 + 2) * basis[c];
      idx1 += ((int)n1 + 2) * basis[c];
    }
    out[OUT_IND + ((size_t)b * 4 + g * 2 + 0) * TN + t] = (float)idx0;
    out[OUT_IND + ((size_t)b * 4 + g * 2 + 1) * TN + t] = (float)idx1;
    qtile[lane][g] = make_float4(q[0], q[1], q[2], q[3]);
    atomicAdd(&hist[(g * 2 + 0) * NBINS + idx0], 1.0f);
    atomicAdd(&hist[(g * 2 + 1) * NBINS + idx1], 1.0f);
  }
  // restage wl4/bl with out-projection weights (no remaining wl4 readers)
  for (int i = tid; i < 1024; i += 256) {
    wl4[i] = ((const float4*)w_out)[i];  // w_out flat: dim*4+c
    bl[i]  = b_out[i];                   // b_out flat: dim
  }

  cg::this_grid().sync();  // counts zeroed; hist/qtile/wl4/bl complete

  // P2a: sparse merge of LDS hist into global counts
  for (int i = tid; i < 4 * NBINS; i += 256) {
    const float v = hist[i];
    if (v != 0.0f) atomicAdd(&counts[i], v);
  }

  // P2b: out-projection for this (b, 64-t) tile, all 1024 dims
  const float4 qa = qtile[lane][0];
  const float4 qb = qtile[lane][1];
  float* op = out + OUT_FEAT + (size_t)b * DIMM * TN + t;
  for (int d = w; d < 512; d += 4) {
    const float4 wv = wl4[d];
    op[(size_t)d * TN] = bl[d] + wv.x * qa.x + wv.y * qa.y + wv.z * qa.z + wv.w * qa.w;
  }
  for (int d = 512 + w; d < 1024; d += 4) {
    const float4 wv = wl4[d];
    op[(size_t)d * TN] = bl[d] + wv.x * qb.x + wv.y * qb.y + wv.z * qb.z + wv.w * qb.w;
  }

  cg::this_grid().sync();  // all atomics to counts visible

  // P3: perplexity, block j in 0..3
  if (bid < 4) {
    const int j = bid;
    double s = 0.0;
    for (int i = tid; i < NBINS; i += 256) s += (double)counts[j * NBINS + i];
    red[tid] = s;
    __syncthreads();
    for (int off = 128; off; off >>= 1) {
      if (tid < off) red[tid] += red[tid + off];
      __syncthreads();
    }
    const double tot = red[0] / 32768.0;  // == 1.0 exactly
    __syncthreads();
    double h = 0.0;
    for (int i = tid; i < NBINS; i += 256) {
      double e  = (double)counts[j * NBINS + i] / 32768.0;
      double e2 = e / (tot + 1e-5);
      h += e2 * log(e2 + 1e-5);
    }
    red[tid] = h;
    __syncthreads();
    for (int off = 128; off; off >>= 1) {
      if (tid < off) red[tid] += red[tid + off];
      __syncthreads();
    }
    if (tid == 0) out[OUT_PERP + j] = (float)exp(-red[0]);
  }
}

// ---------------------------------------------------------------------------
extern "C" void kernel_launch(void* const* d_in, const int* in_sizes, int n_in,
                              void* d_out, int out_size, void* d_ws, size_t ws_size,
                              hipStream_t stream) {
  (void)in_sizes; (void)n_in; (void)out_size; (void)ws_size;

  const float* x     = (const float*)d_in[0];
  const float* w_in  = (const float*)d_in[1];
  const float* b_in  = (const float*)d_in[2];
  const float* w_out = (const float*)d_in[3];
  const float* b_out = (const float*)d_in[4];
  float* out    = (float*)d_out;
  float* counts = (float*)d_ws;   // 2500 floats

  void* args[] = {(void*)&x, (void*)&w_in, (void*)&b_in, (void*)&w_out,
                  (void*)&b_out, (void*)&counts, (void*)&out};
  hipLaunchCooperativeKernel((const void*)gfsq_fused, dim3(512), dim3(256),
                             args, 0, stream);
}

// Round 6
// 97.910 us; speedup vs baseline: 1.9962x; 1.9962x over previous
//
#include <hip/hip_runtime.h>
#include <math.h>

// Problem constants
#define BB    16
#define DIMM  1024
#define TN    2048
#define NBINS 625

// Output layout (floats, concatenated in reference return order)
//   zero: 4 | feat_t: B*DIM*T | perplexity: 4 | ind_t: B*4*T
static constexpr size_t OUT_ZERO = 0;
static constexpr size_t OUT_FEAT = 4;
static constexpr size_t OUT_PERP = 4 + (size_t)BB * DIMM * TN;
static constexpr size_t OUT_IND  = OUT_PERP + 4;

// ---------------------------------------------------------------------------
// A: fully fused per-tile pipeline, NO cross-block dependency, no grid sync.
// One block = (b, 64-t tile), 4 waves.
//   1) stage w_in (float4 per row), wave w accumulates rows [w*256,+256) in
//      f64 (matches np ref), LDS reduce.
//   2) tid<128: f64 tanh/rint FSQ chain -> ind (exact ints) + q -> LDS;
//      all threads restage LDS with w_out/b_out (no remaining w_in readers).
//   3) out-projection: this block writes feat for ALL 1024 dims of its own
//      64-t tile (wave w covers d%4==w; 256B contiguous store per dim-row).
// Blocks skew naturally -> read phase of some overlaps write phase of others.
// ---------------------------------------------------------------------------
__global__ __launch_bounds__(256) void gfsq_a(const float* __restrict__ x,
                                              const float* __restrict__ w_in,
                                              const float* __restrict__ b_in,
                                              const float* __restrict__ w_out,
                                              const float* __restrict__ b_out,
                                              float* __restrict__ out) {
  const int tt   = blockIdx.x;   // 0..31 (64-t tile)
  const int b    = blockIdx.y;   // 0..15
  const int tid  = threadIdx.x;
  const int w    = tid >> 6;
  const int lane = tid & 63;
  const int t    = tt * 64 + lane;

  __shared__ float4 wl4[1024];        // 16 KB: w_in rows, later w_out rows
  __shared__ double sacc[4][4][64];   // 8 KB
  __shared__ float4 qtile[64][2];     // 2 KB
  __shared__ float  bl[1024];         // 4 KB

  for (int i = tid; i < 1024; i += 256) {
    const int g = i >> 9, d = i & 511;
    const float* wp = w_in + g * 2048 + d;
    wl4[i] = make_float4(wp[0], wp[512], wp[1024], wp[1536]);
  }
  __syncthreads();

  // f64 accumulation: wave w owns rows [w*256, w*256+256), coalesced along t
  const float* xp = x + ((size_t)b * DIMM + (size_t)w * 256) * TN + t;
  const int rb = w * 256;
  double a0 = 0.0, a1 = 0.0, a2 = 0.0, a3 = 0.0;
  #pragma unroll 8
  for (int r = 0; r < 256; ++r) {
    double xv = (double)xp[(size_t)r * TN];
    float4 wv = wl4[rb + r];
    a0 += (double)wv.x * xv;
    a1 += (double)wv.y * xv;
    a2 += (double)wv.z * xv;
    a3 += (double)wv.w * xv;
  }
  sacc[w][0][lane] = a0;
  sacc[w][1][lane] = a1;
  sacc[w][2][lane] = a2;
  sacc[w][3][lane] = a3;
  __syncthreads();

  // FSQ chain (tid<128; g = w). All threads then restage wl4/bl with the
  // out-projection weights — safe: no reader of wl4(w_in) remains.
  if (tid < 128) {
    const int g = w;
    const double half_l = (5.0 - 1.0) * (1.0 + 1e-3) / 2.0;  // match np expr
    const int basis[4] = {1, 5, 25, 125};
    float q[4];
    int idx0 = 0, idx1 = 0;
    #pragma unroll
    for (int c = 0; c < 4; ++c) {
      double z = sacc[2 * g][c][lane] + sacc[2 * g + 1][c][lane]
               + (double)b_in[g * 4 + c];
      double n0 = rint(tanh(z) * half_l);          // step 0, s=1
      double r1 = z - 0.5 * n0;
      double n1 = rint(tanh(4.0 * r1) * half_l);   // step 1, s=0.25
      q[c] = (float)(0.5 * n0 + 0.125 * n1);       // exact in f32
      idx0 += ((int)n0 + 2) * basis[c];
      idx1 += ((int)n1 + 2) * basis[c];
    }
    out[OUT_IND + ((size_t)b * 4 + g * 2 + 0) * TN + t] = (float)idx0;
    out[OUT_IND + ((size_t)b * 4 + g * 2 + 1) * TN + t] = (float)idx1;
    qtile[lane][g] = make_float4(q[0], q[1], q[2], q[3]);
  }
  for (int i = tid; i < 1024; i += 256) {
    wl4[i] = ((const float4*)w_out)[i];  // w_out flat: dim*4+c
    bl[i]  = b_out[i];                   // b_out flat: dim
  }
  __syncthreads();

  // out-projection for this (b, 64-t) tile, all 1024 dims
  const float4 qa = qtile[lane][0];
  const float4 qb = qtile[lane][1];
  float* op = out + OUT_FEAT + (size_t)b * DIMM * TN + t;
  #pragma unroll 4
  for (int d = w; d < 512; d += 4) {
    const float4 wv = wl4[d];
    op[(size_t)d * TN] = bl[d] + wv.x * qa.x + wv.y * qa.y + wv.z * qa.z + wv.w * qa.w;
  }
  #pragma unroll 4
  for (int d = 512 + w; d < 1024; d += 4) {
    const float4 wv = wl4[d];
    op[(size_t)d * TN] = bl[d] + wv.x * qb.x + wv.y * qb.y + wv.z * qb.z + wv.w * qb.w;
  }
}

// ---------------------------------------------------------------------------
// B: histogram + perplexity. Block j (of 4) rebuilds histogram j from the ind
// slice A wrote to d_out (LDS float atomics, exact integer counts) — no
// global counts buffer, no zeroing node, deterministic.
// ---------------------------------------------------------------------------
__global__ __launch_bounds__(256) void gfsq_b(float* __restrict__ out) {
  const int j   = blockIdx.x;   // codebook row 0..3
  const int tid = threadIdx.x;

  __shared__ float  hist[NBINS];
  __shared__ double red[256];
  for (int i = tid; i < NBINS; i += 256) hist[i] = 0.0f;
  __syncthreads();
  for (int i = tid; i < BB * TN; i += 256) {
    const int b2 = i >> 11, t = i & 2047;
    const int v = (int)out[OUT_IND + ((size_t)b2 * 4 + j) * TN + t];
    atomicAdd(&hist[v], 1.0f);
  }
  __syncthreads();

  double s = 0.0;
  for (int i = tid; i < NBINS; i += 256) s += (double)hist[i];
  red[tid] = s;
  __syncthreads();
  for (int off = 128; off; off >>= 1) {
    if (tid < off) red[tid] += red[tid + off];
    __syncthreads();
  }
  const double tot = red[0] / 32768.0;  // == 1.0 exactly
  __syncthreads();

  double h = 0.0;
  for (int i = tid; i < NBINS; i += 256) {
    double e  = (double)hist[i] / 32768.0;
    double e2 = e / (tot + 1e-5);
    h += e2 * log(e2 + 1e-5);
  }
  red[tid] = h;
  __syncthreads();
  for (int off = 128; off; off >>= 1) {
    if (tid < off) red[tid] += red[tid + off];
    __syncthreads();
  }
  if (tid == 0) out[OUT_PERP + j] = (float)exp(-red[0]);
  if (j == 0 && tid < 4) out[OUT_ZERO + tid] = 0.0f;
}

// ---------------------------------------------------------------------------
extern "C" void kernel_launch(void* const* d_in, const int* in_sizes, int n_in,
                              void* d_out, int out_size, void* d_ws, size_t ws_size,
                              hipStream_t stream) {
  (void)in_sizes; (void)n_in; (void)out_size; (void)d_ws; (void)ws_size;

  const float* x     = (const float*)d_in[0];
  const float* w_in  = (const float*)d_in[1];
  const float* b_in  = (const float*)d_in[2];
  const float* w_out = (const float*)d_in[3];
  const float* b_out = (const float*)d_in[4];
  float* out = (float*)d_out;

  gfsq_a<<<dim3(32, 16), 256, 0, stream>>>(x, w_in, b_in, w_out, b_out, out);
  gfsq_b<<<4, 256, 0, stream>>>(out);
}